// Round 1
// 25342.830 us; speedup vs baseline: 1.4671x; 1.4671x over previous
//
#include <hip/hip_runtime.h>
#include <math.h>

#define NTH 512
#define BT  32

#define MEAN_OFF 33554432u   // 64*8192*64
#define LV_OFF   34603008u   // MEAN_OFF + 8192*128

// ---- async global->LDS staging (gfx950 global_load_lds, 16B/lane) ----
// LDS dest is linear in tid => wave-uniform base + lane*16, as HW requires.
__device__ __forceinline__ void gl_lds16(const float* g, float* l) {
  __builtin_amdgcn_global_load_lds(
      (const __attribute__((address_space(1))) void*)g,
      (__attribute__((address_space(3))) void*)l,
      16, 0, 0);
}

// one 8192-float (32KB) weight chunk: 512 threads x 4 x 16B
__device__ __forceinline__ void stage_async(const float* __restrict__ g,
                                            float* __restrict__ l, int tid) {
#pragma unroll
  for (int u = 0; u < 4; ++u)
    gl_lds16(g + u * 2048 + tid * 4, l + u * 2048 + tid * 4);
}

// ---- G1-type chunk: A[8 rows x 32 k] @ W[32 x 256], thread owns cols {cc,cc+1} ----
// A rows r1..r1+7 (wave-uniform broadcast reads), row stride SA compile-time.
template<int SA>
__device__ __forceinline__ void g1_chunk(const float* __restrict__ A,
                                         const float* __restrict__ W,
                                         int cc, float (&acc)[8][2]) {
#pragma unroll 4
  for (int j4 = 0; j4 < 8; ++j4) {
    const int kk = j4 * 4;
    float4 a[8];
#pragma unroll
    for (int i = 0; i < 8; ++i)
      a[i] = *(const float4*)(A + i * SA + kk);
    float2 w[4];
#pragma unroll
    for (int j = 0; j < 4; ++j)
      w[j] = *(const float2*)(W + (kk + j) * 256 + cc);
#pragma unroll
    for (int i = 0; i < 8; ++i) {
      const float af[4] = {a[i].x, a[i].y, a[i].z, a[i].w};
#pragma unroll
      for (int j = 0; j < 4; ++j) {
        acc[i][0] = fmaf(af[j], w[j].x, acc[i][0]);
        acc[i][1] = fmaf(af[j], w[j].y, acc[i][1]);
      }
    }
  }
}

// ---- G2 chunk: TMP[4 rows x 64 k] @ W2[64 k x 128], thread owns cols {c2,c2+1} ----
__device__ __forceinline__ void g2_chunk(const float* __restrict__ A,
                                         const float* __restrict__ W,
                                         int c2, float (&acc)[4][2]) {
#pragma unroll 4
  for (int j4 = 0; j4 < 16; ++j4) {
    const int kk = j4 * 4;
    float4 a[4];
#pragma unroll
    for (int i = 0; i < 4; ++i)
      a[i] = *(const float4*)(A + i * 256 + kk);
    float2 w[4];
#pragma unroll
    for (int j = 0; j < 4; ++j)
      w[j] = *(const float2*)(W + (kk + j) * 128 + c2);
#pragma unroll
    for (int i = 0; i < 4; ++i) {
      const float af[4] = {a[i].x, a[i].y, a[i].z, a[i].w};
#pragma unroll
      for (int j = 0; j < 4; ++j) {
        acc[i][0] = fmaf(af[j], w[j].x, acc[i][0]);
        acc[i][1] = fmaf(af[j], w[j].y, acc[i][1]);
      }
    }
  }
}

// ---- decoder G2 chunk: TMP[4 rows x 128 k] @ Wd2[128 k x 64], thread owns col cd ----
__device__ __forceinline__ void gd2_chunk(const float* __restrict__ A,
                                          const float* __restrict__ W,
                                          int cd, float (&acc)[4]) {
#pragma unroll 4
  for (int j4 = 0; j4 < 32; ++j4) {
    const int kk = j4 * 4;
    float4 a[4];
#pragma unroll
    for (int i = 0; i < 4; ++i)
      a[i] = *(const float4*)(A + i * 256 + kk);
    float w[4];
#pragma unroll
    for (int j = 0; j < 4; ++j)
      w[j] = W[(kk + j) * 64 + cd];
#pragma unroll
    for (int i = 0; i < 4; ++i) {
      const float af[4] = {a[i].x, a[i].y, a[i].z, a[i].w};
#pragma unroll
      for (int j = 0; j < 4; ++j)
        acc[i] = fmaf(af[j], w[j], acc[i]);
    }
  }
}

extern "C" __global__ void __launch_bounds__(NTH, 2)
latent_ode_fused(const float* __restrict__ obs,
                 const float* __restrict__ ptimes,
                 const float* __restrict__ eps,
                 const float* __restrict__ Wi2h, const float* __restrict__ bi2h,
                 const float* __restrict__ Wh2o, const float* __restrict__ bh2o,
                 const float* __restrict__ Wode1, const float* __restrict__ bode1,
                 const float* __restrict__ Wode2, const float* __restrict__ bode2,
                 const float* __restrict__ Wdec1, const float* __restrict__ bdec1,
                 const float* __restrict__ Wdec2, const float* __restrict__ bdec2,
                 float* __restrict__ out)
{
  // 112 KB LDS carve (phase-aliased), unchanged layout:
  //  [0,8192)      : encoder H[32][256]   | ODE: ZC[32][128] @0 , TMP[32][256] @4096
  //  [8192,12288)  : encoder XS dbuf 2x[32][64] (aliases TMP upper half; phases disjoint)
  //  [12288,28672) : weight chunk double buffer, 2 x 8192 floats
  __shared__ float smem[28672];
  float* const H     = smem;
  float* const ZC    = smem;
  float* const TMP   = smem + 4096;
  float* const XS    = smem + 8192;
  float* const WBUF0 = smem + 12288;
  float* const WBUF1 = smem + 20480;

  const int tid  = threadIdx.x;
  const int b0   = blockIdx.x * BT;
  const int wave = tid >> 6;
  const int lane = tid & 63;

  // G1-type ownership: wave pair (wave>>1) owns rows r1..r1+7; col half by wave&1
  const int r1 = (wave >> 1) * 8;
  const int cc = (wave & 1) * 128 + lane * 2;
  // G2 ownership: wave owns rows r2..r2+3, lane owns cols {c2,c2+1} of 128
  const int r2 = wave * 4;
  const int c2 = lane * 2;
  // decoder-G2: wave owns rows rd..rd+3, lane owns col cd of 64
  const int rd = wave * 4;
  const int cd = lane;

  // biases in registers
  const float2 be  = *(const float2*)(bi2h + cc);
  const float2 bm  = *(const float2*)(bh2o + cc);
  const float2 bo1 = *(const float2*)(bode1 + cc);
  const float2 bo2 = *(const float2*)(bode2 + c2);
  const float2 bd1 = *(const float2*)(bdec1 + cc);
  const float  bd2 = bdec2[cd];

  // zero H (initial hidden state)
  for (int u = tid; u < 2048; u += NTH)
    *(float4*)(smem + u * 4) = make_float4(0.f, 0.f, 0.f, 0.f);

  // prologue: Xs(s=127) -> XS buf parity1, Wi2h chunk0 -> WBUF0 (async; first barrier drains)
  {
    const int rr = tid >> 4, kp = (tid & 15) * 4;
    gl_lds16(obs + ((size_t)(b0 + rr) * 128 + 127) * 64 + kp, XS + 2048 + tid * 4);
    stage_async(Wi2h, WBUF0, tid);
  }

  float acc[8][2];
#pragma unroll
  for (int i = 0; i < 8; ++i) { acc[i][0] = be.x; acc[i][1] = be.y; }

  // ================= encoder: 128 reversed RNN steps =================
#pragma unroll 1
  for (int it = 0; it < 128; ++it) {
    const int s = 127 - it;
    const float* xs_cur = XS + (s & 1) * 2048;
#pragma unroll 1
    for (int c = 0; c < 10; ++c) {
      __syncthreads();
      if (c == 0) {
        if (it > 0) {
#pragma unroll
          for (int i = 0; i < 8; ++i) {
            *(float2*)(H + (r1 + i) * 256 + cc) =
                make_float2(tanhf(acc[i][0]), tanhf(acc[i][1]));
            acc[i][0] = be.x; acc[i][1] = be.y;
          }
        }
        if (s > 0) {
          const int rr = tid >> 4, kp = (tid & 15) * 4;
          gl_lds16(obs + ((size_t)(b0 + rr) * 128 + (s - 1)) * 64 + kp,
                   XS + ((s - 1) & 1) * 2048 + tid * 4);
        }
      }
      const float* nw = (c < 9) ? (Wi2h + (size_t)(c + 1) * 8192)
                                : ((it < 127) ? Wi2h : Wh2o);
      stage_async(nw, (c & 1) ? WBUF0 : WBUF1, tid);
      const float* wc = (c & 1) ? WBUF1 : WBUF0;
      if (c < 2) g1_chunk<64>(xs_cur + r1 * 64 + 32 * c, wc, cc, acc);
      else       g1_chunk<256>(H + r1 * 256 + 32 * (c - 2), wc, cc, acc);
    }
  }

  // ================= h_final -> (z0_mean, z0_logvar) -> z0 =================
  __syncthreads();
#pragma unroll
  for (int i = 0; i < 8; ++i) {
    *(float2*)(H + (r1 + i) * 256 + cc) =
        make_float2(tanhf(acc[i][0]), tanhf(acc[i][1]));
    acc[i][0] = bm.x; acc[i][1] = bm.y;
  }
#pragma unroll 1
  for (int c = 0; c < 8; ++c) {
    __syncthreads();
    const float* nw = (c < 7) ? (Wh2o + (size_t)(c + 1) * 8192) : Wdec1;
    stage_async(nw, (c & 1) ? WBUF0 : WBUF1, tid);
    g1_chunk<256>(H + r1 * 256 + 32 * c, (c & 1) ? WBUF1 : WBUF0, cc, acc);
  }
  __syncthreads();   // all H reads done
  // publish raw h2o output to TMP[32][256] so mean/logvar pair up in G2-ownership
#pragma unroll
  for (int i = 0; i < 8; ++i)
    *(float2*)(TMP + (r1 + i) * 256 + cc) = make_float2(acc[i][0], acc[i][1]);
  __syncthreads();

  float z[4][2];
#pragma unroll
  for (int i = 0; i < 4; ++i) {
    const float2 m  = *(const float2*)(TMP + (r2 + i) * 256 + c2);
    const float2 lv = *(const float2*)(TMP + (r2 + i) * 256 + c2 + 128);
    const float2 e  = *(const float2*)(eps + (size_t)(b0 + r2 + i) * 128 + c2);
    *(float2*)(out + MEAN_OFF + (size_t)(b0 + r2 + i) * 128 + c2) = m;
    *(float2*)(out + LV_OFF   + (size_t)(b0 + r2 + i) * 128 + c2) = lv;
    z[i][0] = m.x + e.x * expf(0.5f * lv.x);
    z[i][1] = m.y + e.y * expf(0.5f * lv.y);
    *(float2*)(ZC + (r2 + i) * 128 + c2) = make_float2(z[i][0], z[i][1]);
  }

  // ---- decode: hdec = relu(ZC @ Wdec1 + b), P = hdec @ Wdec2 + b -> out[t] ----
  auto decode = [&](int t, const float* nextW) {
    float a1[8][2];
#pragma unroll
    for (int i = 0; i < 8; ++i) { a1[i][0] = bd1.x; a1[i][1] = bd1.y; }
#pragma unroll 1
    for (int c = 0; c < 4; ++c) {
      __syncthreads();
      const float* nw = (c < 3) ? (Wdec1 + (size_t)(c + 1) * 8192) : Wdec2;
      stage_async(nw, (c & 1) ? WBUF0 : WBUF1, tid);
      g1_chunk<128>(ZC + r1 * 128 + 32 * c, (c & 1) ? WBUF1 : WBUF0, cc, a1);
    }
#pragma unroll
    for (int i = 0; i < 8; ++i)
      *(float2*)(TMP + (r1 + i) * 256 + cc) =
          make_float2(fmaxf(a1[i][0], 0.f), fmaxf(a1[i][1], 0.f));
    float a2[4];
#pragma unroll
    for (int i = 0; i < 4; ++i) a2[i] = bd2;
#pragma unroll 1
    for (int c = 0; c < 2; ++c) {
      __syncthreads();
      const float* nw = (c < 1) ? (Wdec2 + 8192) : nextW;
      stage_async(nw, (c & 1) ? WBUF0 : WBUF1, tid);
      gd2_chunk(TMP + rd * 256 + 128 * c, (c & 1) ? WBUF1 : WBUF0, cd, a2);
    }
#pragma unroll
    for (int i = 0; i < 4; ++i)
      out[(size_t)t * 524288 + (size_t)(b0 + rd + i) * 64 + cd] = a2[i];
  };

  // ---- f(zc) = tanh(zc @ Wode1 + b1) @ Wode2 + b2, result in G2-ownership ----
  auto feval = [&](const float* nextW, float (&f)[4][2]) {
    float a1[8][2];
#pragma unroll
    for (int i = 0; i < 8; ++i) { a1[i][0] = bo1.x; a1[i][1] = bo1.y; }
#pragma unroll 1
    for (int c = 0; c < 4; ++c) {
      __syncthreads();
      const float* nw = (c < 3) ? (Wode1 + (size_t)(c + 1) * 8192) : Wode2;
      stage_async(nw, (c & 1) ? WBUF0 : WBUF1, tid);
      g1_chunk<128>(ZC + r1 * 128 + 32 * c, (c & 1) ? WBUF1 : WBUF0, cc, a1);
    }
#pragma unroll
    for (int i = 0; i < 8; ++i)
      *(float2*)(TMP + (r1 + i) * 256 + cc) =
          make_float2(tanhf(a1[i][0]), tanhf(a1[i][1]));
    float a2[4][2];
#pragma unroll
    for (int i = 0; i < 4; ++i) { a2[i][0] = bo2.x; a2[i][1] = bo2.y; }
#pragma unroll 1
    for (int c = 0; c < 4; ++c) {
      __syncthreads();
      const float* nw = (c < 3) ? (Wode2 + (size_t)(c + 1) * 8192) : nextW;
      stage_async(nw, (c & 1) ? WBUF0 : WBUF1, tid);
      g2_chunk(TMP + r2 * 256 + 64 * c, (c & 1) ? WBUF1 : WBUF0, c2, a2);
    }
#pragma unroll
    for (int i = 0; i < 4; ++i) { f[i][0] = a2[i][0]; f[i][1] = a2[i][1]; }
  };

  decode(0, Wode1);

  // ================= 63 intervals x 4 RK4 substeps =================
  float kacc[4][2];
#pragma unroll 1
  for (int t = 0; t < 63; ++t) {
    const float dt = (ptimes[t + 1] - ptimes[t]) * 0.25f;
#pragma unroll 1
    for (int ss = 0; ss < 4; ++ss) {
      float f[4][2];
      // k1
      feval(Wode1, f);
      {
        const float h = 0.5f * dt;
#pragma unroll
        for (int i = 0; i < 4; ++i) {
          float2 v;
          kacc[i][0] = f[i][0]; v.x = fmaf(h, f[i][0], z[i][0]);
          kacc[i][1] = f[i][1]; v.y = fmaf(h, f[i][1], z[i][1]);
          *(float2*)(ZC + (r2 + i) * 128 + c2) = v;
        }
      }
      // k2
      feval(Wode1, f);
      {
        const float h = 0.5f * dt;
#pragma unroll
        for (int i = 0; i < 4; ++i) {
          float2 v;
          kacc[i][0] = fmaf(2.f, f[i][0], kacc[i][0]); v.x = fmaf(h, f[i][0], z[i][0]);
          kacc[i][1] = fmaf(2.f, f[i][1], kacc[i][1]); v.y = fmaf(h, f[i][1], z[i][1]);
          *(float2*)(ZC + (r2 + i) * 128 + c2) = v;
        }
      }
      // k3
      feval(Wode1, f);
      {
#pragma unroll
        for (int i = 0; i < 4; ++i) {
          float2 v;
          kacc[i][0] = fmaf(2.f, f[i][0], kacc[i][0]); v.x = fmaf(dt, f[i][0], z[i][0]);
          kacc[i][1] = fmaf(2.f, f[i][1], kacc[i][1]); v.y = fmaf(dt, f[i][1], z[i][1]);
          *(float2*)(ZC + (r2 + i) * 128 + c2) = v;
        }
      }
      // k4 + state update
      feval((ss < 3) ? Wode1 : Wdec1, f);
      {
        const float h6 = dt * (1.0f / 6.0f);
#pragma unroll
        for (int i = 0; i < 4; ++i) {
          float2 v;
          z[i][0] = fmaf(h6, kacc[i][0] + f[i][0], z[i][0]); v.x = z[i][0];
          z[i][1] = fmaf(h6, kacc[i][1] + f[i][1], z[i][1]); v.y = z[i][1];
          *(float2*)(ZC + (r2 + i) * 128 + c2) = v;
        }
      }
    }
    decode(t + 1, Wode1);
  }
}

extern "C" void kernel_launch(void* const* d_in, const int* in_sizes, int n_in,
                              void* d_out, int out_size, void* d_ws, size_t ws_size,
                              hipStream_t stream) {
  const float* obs    = (const float*)d_in[0];
  // d_in[1] = observed_times (unused by the reference)
  const float* ptimes = (const float*)d_in[2];
  const float* eps    = (const float*)d_in[3];
  const float* Wi2h   = (const float*)d_in[4];
  const float* bi2h   = (const float*)d_in[5];
  const float* Wh2o   = (const float*)d_in[6];
  const float* bh2o   = (const float*)d_in[7];
  const float* Wode1  = (const float*)d_in[8];
  const float* bode1  = (const float*)d_in[9];
  const float* Wode2  = (const float*)d_in[10];
  const float* bode2  = (const float*)d_in[11];
  const float* Wdec1  = (const float*)d_in[12];
  const float* bdec1  = (const float*)d_in[13];
  const float* Wdec2  = (const float*)d_in[14];
  const float* bdec2  = (const float*)d_in[15];

  latent_ode_fused<<<dim3(8192 / BT), dim3(NTH), 0, stream>>>(
      obs, ptimes, eps, Wi2h, bi2h, Wh2o, bh2o,
      Wode1, bode1, Wode2, bode2, Wdec1, bdec1, Wdec2, bdec2,
      (float*)d_out);
}